// Round 1
// baseline (636.027 us; speedup 1.0000x reference)
//
#include <hip/hip_runtime.h>
#include <stdint.h>

#define S_LEN 4096
#define DIM   2048
#define NH    16
#define HD    128
#define N3    6144

typedef unsigned short u16;
typedef __attribute__((ext_vector_type(8))) short bfrag;   // 8 x bf16 (4 VGPRs)
typedef __attribute__((ext_vector_type(4))) float ffrag;   // 4 x f32 acc

__device__ __forceinline__ u16 f2bf(float f) {
  union { float f; unsigned u; } v; v.f = f;
  unsigned r = v.u + 0x7fffu + ((v.u >> 16) & 1u);  // RNE
  return (u16)(r >> 16);
}

__device__ __forceinline__ void gload16(const void* g, void* l) {
  __builtin_amdgcn_global_load_lds((const __attribute__((address_space(1))) void*)g,
                                   (__attribute__((address_space(3))) void*)l, 16, 0, 0);
}

// ---------------- fp32 -> bf16 elementwise ----------------
__global__ void k_cvt(const float* __restrict__ in, u16* __restrict__ out, int n8) {
  int i = blockIdx.x * blockDim.x + threadIdx.x;
  if (i >= n8) return;
  const float4* p = (const float4*)(in + (size_t)i * 8);
  float4 a = p[0], b = p[1];
  bfrag o;
  o[0] = (short)f2bf(a.x); o[1] = (short)f2bf(a.y);
  o[2] = (short)f2bf(a.z); o[3] = (short)f2bf(a.w);
  o[4] = (short)f2bf(b.x); o[5] = (short)f2bf(b.y);
  o[6] = (short)f2bf(b.z); o[7] = (short)f2bf(b.w);
  *(bfrag*)(out + (size_t)i * 8) = o;
}

// ---------------- fp32 [rows][cols] -> bf16 [cols][rows] ----------------
__global__ void k_trcvt(const float* __restrict__ in, u16* __restrict__ out,
                        int rows, int cols) {
  __shared__ float t[32][33];
  int c0 = blockIdx.x * 32, r0 = blockIdx.y * 32;
  int tx = threadIdx.x, ty = threadIdx.y;
  #pragma unroll
  for (int i = ty; i < 32; i += 8)
    t[i][tx] = in[(size_t)(r0 + i) * cols + c0 + tx];
  __syncthreads();
  #pragma unroll
  for (int i = ty; i < 32; i += 8)
    out[(size_t)(c0 + i) * rows + r0 + tx] = f2bf(t[tx][i]);
}

// ---------------- bf16 transpose of V section of qkv -> vt[2048][4096] ----------------
__global__ void k_trv(const u16* __restrict__ qkv, u16* __restrict__ vt) {
  __shared__ u16 t[32][34];
  int c0 = blockIdx.x * 32, r0 = blockIdx.y * 32;  // c: head*D dim, r: s dim
  int tx = threadIdx.x, ty = threadIdx.y;
  #pragma unroll
  for (int i = ty; i < 32; i += 8)
    t[i][tx] = qkv[(size_t)(r0 + i) * N3 + 2 * DIM + c0 + tx];
  __syncthreads();
  #pragma unroll
  for (int i = ty; i < 32; i += 8)
    vt[(size_t)(c0 + i) * S_LEN + r0 + tx] = t[tx][i];
}

// ---------------- bf16 GEMM: C[M][N] = A[M][K] * Bt[N][K]^T ----------------
// m97 structure: 128x128 tile, BK=64, 4 waves (2x2), 16x16x32 MFMA, 4x4 acc/wave.
// XOR swizzle ((row&7)<<4) on the 128B LDS rows, applied by pre-swizzling the
// global source address (global_load_lds dest must stay linear).
template<int OUT_BF16>
__global__ __launch_bounds__(256) void k_gemm(const u16* __restrict__ A,
                                              const u16* __restrict__ Bt,
                                              void* __restrict__ C,
                                              int M, int N, int K) {
  __shared__ __align__(16) u16 Al[128 * 64];
  __shared__ __align__(16) u16 Bl[128 * 64];
  const int tid = threadIdx.x;
  const int lane = tid & 63;
  const int w = tid >> 6, wr = w >> 1, wc = w & 1;
  const int fr = lane & 15, fq = lane >> 4;

  // bijective XCD swizzle (m204)
  int nwg = gridDim.x, bid = blockIdx.x;
  int qq = nwg >> 3, r8 = nwg & 7;
  int xcd = bid & 7, ord = bid >> 3;
  int sb = (xcd < r8 ? xcd * (qq + 1) : r8 * (qq + 1) + (xcd - r8) * qq) + ord;
  const int nbx = N >> 7;
  const int bx = sb % nbx, by = sb / nbx;
  const size_t row0 = (size_t)by << 7, col0 = (size_t)bx << 7;

  const int srow = tid >> 3;        // staging row within 32-row round
  const int scb  = (tid & 7) << 4;  // staging byte-col

  ffrag acc[4][4] = {};

  for (int k0 = 0; k0 < K; k0 += 64) {
    __syncthreads();
    #pragma unroll
    for (int r = 0; r < 4; ++r) {
      int trow = r * 32 + srow;
      int cb = scb ^ ((trow & 7) << 4);
      gload16(A + (row0 + trow) * K + k0 + (cb >> 1),
              (char*)Al + r * 4096 + w * 1024);
    }
    #pragma unroll
    for (int r = 0; r < 4; ++r) {
      int trow = r * 32 + srow;
      int cb = scb ^ ((trow & 7) << 4);
      gload16(Bt + (col0 + trow) * K + k0 + (cb >> 1),
              (char*)Bl + r * 4096 + w * 1024);
    }
    __syncthreads();
    #pragma unroll
    for (int kk = 0; kk < 2; ++kk) {
      bfrag af[4], bf[4];
      #pragma unroll
      for (int m = 0; m < 4; ++m) {
        int row = wr * 64 + m * 16 + fr;
        af[m] = *(const bfrag*)((const char*)Al + row * 128 +
                                ((kk * 64 + fq * 16) ^ ((row & 7) << 4)));
      }
      #pragma unroll
      for (int n = 0; n < 4; ++n) {
        int row = wc * 64 + n * 16 + fr;
        bf[n] = *(const bfrag*)((const char*)Bl + row * 128 +
                                ((kk * 64 + fq * 16) ^ ((row & 7) << 4)));
      }
      #pragma unroll
      for (int m = 0; m < 4; ++m)
        #pragma unroll
        for (int n = 0; n < 4; ++n)
          acc[m][n] = __builtin_amdgcn_mfma_f32_16x16x32_bf16(af[m], bf[n], acc[m][n], 0, 0, 0);
    }
  }
  // epilogue: C/D layout col=lane&15, row=(lane>>4)*4+reg  [m89]
  #pragma unroll
  for (int m = 0; m < 4; ++m) {
    size_t grow = row0 + wr * 64 + m * 16 + fq * 4;
    #pragma unroll
    for (int n = 0; n < 4; ++n) {
      size_t gcol = col0 + wc * 64 + n * 16 + fr;
      #pragma unroll
      for (int r = 0; r < 4; ++r) {
        if (OUT_BF16) ((u16*)C)[(grow + r) * N + gcol] = f2bf(acc[m][n][r]);
        else          ((float*)C)[(grow + r) * N + gcol] = acc[m][n][r];
      }
    }
  }
}

// ---------------- flash attention: block = (128 q-rows, 1 head), 8 waves ----------------
__global__ __launch_bounds__(512) void k_attn(const u16* __restrict__ qkv,
                                              const u16* __restrict__ vt,
                                              u16* __restrict__ o) {
  __shared__ __align__(16) u16 Kl[64 * 128];      // [j][d] 256B rows, swizzled
  __shared__ __align__(16) u16 Vl[128 * 64];      // [d][j] 128B rows, swizzled
  __shared__ __align__(16) u16 Pl[8][16 * 64];    // per-wave P, 128B rows, swizzled
  const int tid = threadIdx.x;
  const int lane = tid & 63;
  const int wq = tid >> 6;           // wave -> 16 q-rows
  const int fr = lane & 15, fq = lane >> 4;
  const int qt = blockIdx.x, h = blockIdx.y;
  const int q0 = qt << 7;

  // Q fragments in registers (K=128 -> 4 frags)
  bfrag qf[4];
  {
    const u16* qrow = qkv + (size_t)(q0 + wq * 16 + fr) * N3 + h * HD + fq * 8;
    #pragma unroll
    for (int kk = 0; kk < 4; ++kk)
      qf[kk] = *(const bfrag*)(qrow + kk * 32);
  }
  float mrow[4] = {-1e30f, -1e30f, -1e30f, -1e30f};
  float lrow[4] = {0.f, 0.f, 0.f, 0.f};
  ffrag oacc[8] = {};

  int ntiles = (q0 + 192) >> 6;                  // j <= i+1 -> up to q0+128
  if (ntiles > (S_LEN >> 6)) ntiles = S_LEN >> 6;
  const u16* kbase = qkv + DIM + (size_t)h * HD;
  const u16* vbase = vt + (size_t)h * HD * S_LEN;
  const float scale = 0.088388347648318447f;     // 1/sqrt(128)

  for (int jt = 0; jt < ntiles; ++jt) {
    const int j0 = jt << 6;
    __syncthreads();
    // stage K tile [64][128] (2 rounds x 512 lanes x 16B)
    #pragma unroll
    for (int r = 0; r < 2; ++r) {
      int slot = r * 512 + tid;
      int trow = slot >> 4;
      int cb = ((slot & 15) << 4) ^ ((trow & 7) << 4);
      gload16(kbase + (size_t)(j0 + trow) * N3 + (cb >> 1),
              (char*)Kl + r * 8192 + wq * 1024);
    }
    // stage Vt tile [128][64]
    #pragma unroll
    for (int r = 0; r < 2; ++r) {
      int slot = r * 512 + tid;
      int trow = slot >> 3;
      int cb = ((slot & 7) << 4) ^ ((trow & 7) << 4);
      gload16(vbase + (size_t)trow * S_LEN + j0 + (cb >> 1),
              (char*)Vl + r * 8192 + wq * 1024);
    }
    __syncthreads();

    // S = Q K^T (K rows read as B-fragments)
    ffrag sacc[4] = {};
    #pragma unroll
    for (int n = 0; n < 4; ++n) {
      int row = n * 16 + fr;
      #pragma unroll
      for (int kk = 0; kk < 4; ++kk) {
        bfrag kf = *(const bfrag*)((const char*)Kl + row * 256 +
                                   ((kk * 64 + fq * 16) ^ ((row & 7) << 4)));
        sacc[n] = __builtin_amdgcn_mfma_f32_16x16x32_bf16(qf[kk], kf, sacc[n], 0, 0, 0);
      }
    }
    // scale + mask (allowed j <= i+1) + row max
    float pmax[4] = {-1e30f, -1e30f, -1e30f, -1e30f};
    #pragma unroll
    for (int n = 0; n < 4; ++n) {
      int j = j0 + n * 16 + fr;
      #pragma unroll
      for (int r = 0; r < 4; ++r) {
        int i = q0 + wq * 16 + fq * 4 + r;
        float s = sacc[n][r] * scale;
        if (j > i + 1) s = -1e30f;
        sacc[n][r] = s;
        pmax[r] = fmaxf(pmax[r], s);
      }
    }
    #pragma unroll
    for (int r = 0; r < 4; ++r)
      #pragma unroll
      for (int off = 1; off < 16; off <<= 1)
        pmax[r] = fmaxf(pmax[r], __shfl_xor(pmax[r], off));

    float alpha[4], rsum[4];
    #pragma unroll
    for (int r = 0; r < 4; ++r) {
      float mnew = fmaxf(mrow[r], pmax[r]);
      alpha[r] = __expf(mrow[r] - mnew);
      mrow[r] = mnew;
      rsum[r] = 0.f;
    }
    // P = exp(S - m), write bf16 to per-wave LDS (swizzled)
    u16* pl = (u16*)Pl[wq];
    #pragma unroll
    for (int n = 0; n < 4; ++n) {
      #pragma unroll
      for (int r = 0; r < 4; ++r) {
        float p = __expf(sacc[n][r] - mrow[r]);
        rsum[r] += p;
        int prow = fq * 4 + r;
        int pcb = ((n * 16 + fr) << 1) ^ ((prow & 7) << 4);
        *(u16*)((char*)pl + prow * 128 + pcb) = f2bf(p);
      }
    }
    #pragma unroll
    for (int r = 0; r < 4; ++r) {
      #pragma unroll
      for (int off = 1; off < 16; off <<= 1)
        rsum[r] += __shfl_xor(rsum[r], off);
      lrow[r] = lrow[r] * alpha[r] + rsum[r];
    }
    #pragma unroll
    for (int d = 0; d < 8; ++d)
      #pragma unroll
      for (int r = 0; r < 4; ++r)
        oacc[d][r] *= alpha[r];

    asm volatile("s_waitcnt lgkmcnt(0)" ::: "memory");  // P writes visible to own wave reads

    // O += P V  (P as A-frag from LDS, Vt rows as B-frags)
    #pragma unroll
    for (int kf = 0; kf < 2; ++kf) {
      bfrag pf = *(const bfrag*)((const char*)pl + fr * 128 +
                                 ((kf * 64 + fq * 16) ^ ((fr & 7) << 4)));
      #pragma unroll
      for (int d = 0; d < 8; ++d) {
        int row = d * 16 + fr;
        bfrag vf = *(const bfrag*)((const char*)Vl + row * 128 +
                                   ((kf * 64 + fq * 16) ^ ((row & 7) << 4)));
        oacc[d] = __builtin_amdgcn_mfma_f32_16x16x32_bf16(pf, vf, oacc[d], 0, 0, 0);
      }
    }
  }
  // normalize + store o (bf16, row-major [S][DIM])
  float linv[4];
  #pragma unroll
  for (int r = 0; r < 4; ++r) linv[r] = 1.f / lrow[r];
  #pragma unroll
  for (int d = 0; d < 8; ++d) {
    #pragma unroll
    for (int r = 0; r < 4; ++r) {
      size_t row = q0 + wq * 16 + fq * 4 + r;
      size_t col = (size_t)h * HD + d * 16 + fr;
      o[row * DIM + col] = f2bf(oacc[d][r] * linv[r]);
    }
  }
}

extern "C" void kernel_launch(void* const* d_in, const int* in_sizes, int n_in,
                              void* d_out, int out_size, void* d_ws, size_t ws_size,
                              hipStream_t stream) {
  const float* x     = (const float*)d_in[0];
  const float* w_qkv = (const float*)d_in[1];
  const float* w_o   = (const float*)d_in[2];
  float* out = (float*)d_out;

  // workspace layout (128 MiB total, all 16B-aligned)
  u16* xb    = (u16*)d_ws;                          // [4096][2048]
  u16* wqkvT = xb    + (size_t)S_LEN * DIM;         // [6144][2048]
  u16* woT   = wqkvT + (size_t)DIM * N3;            // [2048][2048]
  u16* qkvb  = woT   + (size_t)DIM * DIM;           // [4096][6144]
  u16* vtb   = qkvb  + (size_t)S_LEN * N3;          // [2048][4096]
  u16* ob    = vtb   + (size_t)DIM * S_LEN;         // [4096][2048]

  k_cvt<<<(S_LEN * DIM / 8 + 255) / 256, 256, 0, stream>>>(x, xb, S_LEN * DIM / 8);
  k_trcvt<<<dim3(N3 / 32, DIM / 32), dim3(32, 8), 0, stream>>>(w_qkv, wqkvT, DIM, N3);
  k_trcvt<<<dim3(DIM / 32, DIM / 32), dim3(32, 8), 0, stream>>>(w_o, woT, DIM, DIM);

  k_gemm<1><<<(S_LEN / 128) * (N3 / 128), 256, 0, stream>>>(xb, wqkvT, qkvb, S_LEN, N3, DIM);
  k_trv<<<dim3(DIM / 32, S_LEN / 32), dim3(32, 8), 0, stream>>>(qkvb, vtb);
  k_attn<<<dim3(S_LEN / 128, NH), 512, 0, stream>>>(qkvb, vtb, ob);
  k_gemm<0><<<(S_LEN / 128) * (DIM / 128), 256, 0, stream>>>(ob, woT, out, S_LEN, DIM, DIM);
}

// Round 4
// 585.207 us; speedup vs baseline: 1.0868x; 1.0868x over previous
//
#include <hip/hip_runtime.h>
#include <stdint.h>

#define S_LEN 4096
#define DIM   2048
#define NH    16
#define HD    128
#define N3    6144

typedef unsigned short u16;
typedef __attribute__((ext_vector_type(8))) short bfrag;   // 8 x bf16 (4 VGPRs)
typedef __attribute__((ext_vector_type(4))) float ffrag;   // 4 x f32 acc

__device__ __forceinline__ u16 f2bf(float f) {
  union { float f; unsigned u; } v; v.f = f;
  unsigned r = v.u + 0x7fffu + ((v.u >> 16) & 1u);  // RNE
  return (u16)(r >> 16);
}

// 2^x via the hardware transcendental (no libm; v_exp_f32 IS exp2)
__device__ __forceinline__ float exp2_hw(float x) {
  float r;
  asm("v_exp_f32 %0, %1" : "=v"(r) : "v"(x));
  return r;
}

__device__ __forceinline__ void gload16(const void* g, void* l) {
  __builtin_amdgcn_global_load_lds((const __attribute__((address_space(1))) void*)g,
                                   (__attribute__((address_space(3))) void*)l, 16, 0, 0);
}

// ---------------- fp32 -> bf16 elementwise ----------------
__global__ void k_cvt(const float* __restrict__ in, u16* __restrict__ out, int n8) {
  int i = blockIdx.x * blockDim.x + threadIdx.x;
  if (i >= n8) return;
  const float4* p = (const float4*)(in + (size_t)i * 8);
  float4 a = p[0], b = p[1];
  bfrag o;
  o[0] = (short)f2bf(a.x); o[1] = (short)f2bf(a.y);
  o[2] = (short)f2bf(a.z); o[3] = (short)f2bf(a.w);
  o[4] = (short)f2bf(b.x); o[5] = (short)f2bf(b.y);
  o[6] = (short)f2bf(b.z); o[7] = (short)f2bf(b.w);
  *(bfrag*)(out + (size_t)i * 8) = o;
}

// ---------------- fp32 [rows][cols] -> bf16 [cols][rows] ----------------
__global__ void k_trcvt(const float* __restrict__ in, u16* __restrict__ out,
                        int rows, int cols) {
  __shared__ float t[32][33];
  int c0 = blockIdx.x * 32, r0 = blockIdx.y * 32;
  int tx = threadIdx.x, ty = threadIdx.y;
  #pragma unroll
  for (int i = ty; i < 32; i += 8)
    t[i][tx] = in[(size_t)(r0 + i) * cols + c0 + tx];
  __syncthreads();
  #pragma unroll
  for (int i = ty; i < 32; i += 8)
    out[(size_t)(c0 + i) * rows + r0 + tx] = f2bf(t[tx][i]);
}

// ---------------- bf16 transpose of V section of qkv -> vt[2048][4096] ----------------
__global__ void k_trv(const u16* __restrict__ qkv, u16* __restrict__ vt) {
  __shared__ u16 t[32][34];
  int c0 = blockIdx.x * 32, r0 = blockIdx.y * 32;  // c: head*D dim, r: s dim
  int tx = threadIdx.x, ty = threadIdx.y;
  #pragma unroll
  for (int i = ty; i < 32; i += 8)
    t[i][tx] = qkv[(size_t)(r0 + i) * N3 + 2 * DIM + c0 + tx];
  __syncthreads();
  #pragma unroll
  for (int i = ty; i < 32; i += 8)
    vt[(size_t)(c0 + i) * S_LEN + r0 + tx] = t[tx][i];
}

// ---------------- bf16 GEMM: C[M][N] = A[M][K] * Bt[N][K]^T ----------------
template<int OUT_BF16>
__global__ __launch_bounds__(256) void k_gemm(const u16* __restrict__ A,
                                              const u16* __restrict__ Bt,
                                              void* __restrict__ C,
                                              int M, int N, int K) {
  __shared__ __align__(16) u16 Al[128 * 64];
  __shared__ __align__(16) u16 Bl[128 * 64];
  const int tid = threadIdx.x;
  const int lane = tid & 63;
  const int w = tid >> 6, wr = w >> 1, wc = w & 1;
  const int fr = lane & 15, fq = lane >> 4;

  // bijective XCD swizzle (m204)
  int nwg = gridDim.x, bid = blockIdx.x;
  int qq = nwg >> 3, r8 = nwg & 7;
  int xcd = bid & 7, ord = bid >> 3;
  int sb = (xcd < r8 ? xcd * (qq + 1) : r8 * (qq + 1) + (xcd - r8) * qq) + ord;
  const int nbx = N >> 7;
  const int bx = sb % nbx, by = sb / nbx;
  const size_t row0 = (size_t)by << 7, col0 = (size_t)bx << 7;

  const int srow = tid >> 3;        // staging row within 32-row round
  const int scb  = (tid & 7) << 4;  // staging byte-col

  ffrag acc[4][4] = {};

  for (int k0 = 0; k0 < K; k0 += 64) {
    __syncthreads();
    #pragma unroll
    for (int r = 0; r < 4; ++r) {
      int trow = r * 32 + srow;
      int cb = scb ^ ((trow & 7) << 4);
      gload16(A + (row0 + trow) * K + k0 + (cb >> 1),
              (char*)Al + r * 4096 + w * 1024);
    }
    #pragma unroll
    for (int r = 0; r < 4; ++r) {
      int trow = r * 32 + srow;
      int cb = scb ^ ((trow & 7) << 4);
      gload16(Bt + (col0 + trow) * K + k0 + (cb >> 1),
              (char*)Bl + r * 4096 + w * 1024);
    }
    __syncthreads();
    #pragma unroll
    for (int kk = 0; kk < 2; ++kk) {
      bfrag af[4], bf[4];
      #pragma unroll
      for (int m = 0; m < 4; ++m) {
        int row = wr * 64 + m * 16 + fr;
        af[m] = *(const bfrag*)((const char*)Al + row * 128 +
                                ((kk * 64 + fq * 16) ^ ((row & 7) << 4)));
      }
      #pragma unroll
      for (int n = 0; n < 4; ++n) {
        int row = wc * 64 + n * 16 + fr;
        bf[n] = *(const bfrag*)((const char*)Bl + row * 128 +
                                ((kk * 64 + fq * 16) ^ ((row & 7) << 4)));
      }
      #pragma unroll
      for (int m = 0; m < 4; ++m)
        #pragma unroll
        for (int n = 0; n < 4; ++n)
          acc[m][n] = __builtin_amdgcn_mfma_f32_16x16x32_bf16(af[m], bf[n], acc[m][n], 0, 0, 0);
    }
  }
  // epilogue: C/D layout col=lane&15, row=(lane>>4)*4+reg  [m89]
  #pragma unroll
  for (int m = 0; m < 4; ++m) {
    size_t grow = row0 + wr * 64 + m * 16 + fq * 4;
    #pragma unroll
    for (int n = 0; n < 4; ++n) {
      size_t gcol = col0 + wc * 64 + n * 16 + fr;
      #pragma unroll
      for (int r = 0; r < 4; ++r) {
        if (OUT_BF16) ((u16*)C)[(grow + r) * N + gcol] = f2bf(acc[m][n][r]);
        else          ((float*)C)[(grow + r) * N + gcol] = acc[m][n][r];
      }
    }
  }
}

// ---------------- flash attention ----------------
// 1-D grid of 512 blocks. Schedule: XCD x gets heads {2x, 2x+1} (K/V fits 4MB L2);
// head 2x runs qt descending, head 2x+1 qt ascending -> each CU's two resident
// blocks sum to a constant ~68 KV-tile iterations (balance). K/V double-buffered
// in LDS; stage(t+1) issued before compute(t); one barrier per tile.
__global__ __launch_bounds__(512) void k_attn(const u16* __restrict__ qkv,
                                              const u16* __restrict__ vt,
                                              u16* __restrict__ o) {
  __shared__ __align__(16) u16 Kl[2][64 * 128];   // [j][d] 256B rows, swizzled
  __shared__ __align__(16) u16 Vl[2][128 * 64];   // [d][j] 128B rows, swizzled
  __shared__ __align__(16) u16 Pl[8][16 * 64];    // per-wave P, 128B rows, swizzled
  const int tid = threadIdx.x;
  const int lane = tid & 63;
  const int wq = tid >> 6;           // wave -> 16 q-rows
  const int fr = lane & 15, fq = lane >> 4;

  // schedule mapping
  const int bid = blockIdx.x;
  const int sb = (bid & 7) * 64 + (bid >> 3);     // m204: contiguous sb per XCD
  const int h = sb >> 5;                          // 0..15
  const int tt = sb & 31;
  const int qt = (h & 1) ? tt : (31 - tt);        // pair heavy with light per CU
  const int q0 = qt << 7;
  const int iw0 = q0 + wq * 16;                   // wave's first q-row

  // Q fragments in registers (K=128 -> 4 frags)
  bfrag qf[4];
  {
    const u16* qrow = qkv + (size_t)(iw0 + fr) * N3 + h * HD + fq * 8;
    #pragma unroll
    for (int kk = 0; kk < 4; ++kk)
      qf[kk] = *(const bfrag*)(qrow + kk * 32);
  }
  float mrow[4] = {-3e38f, -3e38f, -3e38f, -3e38f};
  float lrow[4] = {0.f, 0.f, 0.f, 0.f};
  ffrag oacc[8] = {};

  int ntiles = (q0 + 192) >> 6;                  // j <= i+1 -> up to q0+128
  if (ntiles > (S_LEN >> 6)) ntiles = S_LEN >> 6;
  const u16* kbase = qkv + DIM + (size_t)h * HD;
  const u16* vbase = vt + (size_t)h * HD * S_LEN;
  const float sc2 = 0.088388347648318447f * 1.4426950408889634f;  // scale*log2(e)

  // staging helper (inlined twice)
#define STAGE_KV(J0, KD, VD)                                               \
  do {                                                                     \
    _Pragma("unroll")                                                      \
    for (int r = 0; r < 2; ++r) {                                          \
      int slot = r * 512 + tid;                                            \
      int trow = slot >> 4;                                                \
      int cb = ((slot & 15) << 4) ^ ((trow & 7) << 4);                     \
      gload16(kbase + (size_t)((J0) + trow) * N3 + (cb >> 1),              \
              (char*)(KD) + r * 8192 + wq * 1024);                         \
    }                                                                      \
    _Pragma("unroll")                                                      \
    for (int r = 0; r < 2; ++r) {                                          \
      int slot = r * 512 + tid;                                            \
      int trow = slot >> 3;                                                \
      int cb = ((slot & 7) << 4) ^ ((trow & 7) << 4);                      \
      gload16(vbase + (size_t)trow * S_LEN + (J0) + (cb >> 1),             \
              (char*)(VD) + r * 8192 + wq * 1024);                         \
    }                                                                      \
  } while (0)

  STAGE_KV(0, Kl[0], Vl[0]);
  __syncthreads();   // drains vmcnt(0): buf0 ready
  int cur = 0;

  for (int jt = 0; jt < ntiles; ++jt) {
    const int j0 = jt << 6;
    if (jt + 1 < ntiles)
      STAGE_KV((jt + 1) << 6, Kl[cur ^ 1], Vl[cur ^ 1]);   // prefetch under compute

    const bool active = (j0 <= iw0 + 16);        // wave has any allowed column
    if (active) {
      const char* Kc = (const char*)Kl[cur];
      const char* Vc = (const char*)Vl[cur];
      // S = Q K^T (K rows read as B-fragments)
      ffrag sacc[4] = {};
      #pragma unroll
      for (int n = 0; n < 4; ++n) {
        int row = n * 16 + fr;
        #pragma unroll
        for (int kk = 0; kk < 4; ++kk) {
          bfrag kf = *(const bfrag*)(Kc + row * 256 +
                                     ((kk * 64 + fq * 16) ^ ((row & 7) << 4)));
          sacc[n] = __builtin_amdgcn_mfma_f32_16x16x32_bf16(qf[kk], kf, sacc[n], 0, 0, 0);
        }
      }
      // mask (diagonal tiles only) + row max over raw scores
      const bool needmask = (j0 + 63) > (iw0 + 1);
      float pmax[4] = {-3e38f, -3e38f, -3e38f, -3e38f};
      #pragma unroll
      for (int n = 0; n < 4; ++n) {
        int j = j0 + n * 16 + fr;
        #pragma unroll
        for (int r = 0; r < 4; ++r) {
          float s = sacc[n][r];
          if (needmask) {
            int i = iw0 + fq * 4 + r;
            if (j > i + 1) s = -3e38f;
            sacc[n][r] = s;
          }
          pmax[r] = fmaxf(pmax[r], s);
        }
      }
      #pragma unroll
      for (int r = 0; r < 4; ++r)
        #pragma unroll
        for (int off = 1; off < 16; off <<= 1)
          pmax[r] = fmaxf(pmax[r], __shfl_xor(pmax[r], off));

      // T13 defer-max: rescale only when the new max meaningfully exceeds m
      float needv = fmaxf(fmaxf(pmax[0] - mrow[0], pmax[1] - mrow[1]),
                          fmaxf(pmax[2] - mrow[2], pmax[3] - mrow[3]));
      if (!__all(needv * sc2 <= 8.0f)) {
        #pragma unroll
        for (int r = 0; r < 4; ++r) {
          float mnew = fmaxf(mrow[r], pmax[r]);
          float alpha = exp2_hw((mrow[r] - mnew) * sc2);
          mrow[r] = mnew;
          lrow[r] *= alpha;
          #pragma unroll
          for (int d = 0; d < 8; ++d) oacc[d][r] *= alpha;
        }
      }

      // P = exp2((S - m)*sc2), bf16 into per-wave LDS (swizzled)
      u16* pl = (u16*)Pl[wq];
      float rsum[4] = {0.f, 0.f, 0.f, 0.f};
      #pragma unroll
      for (int n = 0; n < 4; ++n) {
        #pragma unroll
        for (int r = 0; r < 4; ++r) {
          float p = exp2_hw((sacc[n][r] - mrow[r]) * sc2);
          rsum[r] += p;
          int prow = fq * 4 + r;
          int pcb = ((n * 16 + fr) << 1) ^ ((prow & 7) << 4);
          *(u16*)((char*)pl + prow * 128 + pcb) = f2bf(p);
        }
      }
      #pragma unroll
      for (int r = 0; r < 4; ++r) {
        #pragma unroll
        for (int off = 1; off < 16; off <<= 1)
          rsum[r] += __shfl_xor(rsum[r], off);
        lrow[r] += rsum[r];
      }

      asm volatile("s_waitcnt lgkmcnt(0)" ::: "memory");  // P visible to own-wave reads

      // O += P V
      #pragma unroll
      for (int kf2 = 0; kf2 < 2; ++kf2) {
        bfrag pf = *(const bfrag*)((const char*)pl + fr * 128 +
                                   ((kf2 * 64 + fq * 16) ^ ((fr & 7) << 4)));
        #pragma unroll
        for (int d = 0; d < 8; ++d) {
          int row = d * 16 + fr;
          bfrag vf = *(const bfrag*)(Vc + row * 128 +
                                     ((kf2 * 64 + fq * 16) ^ ((row & 7) << 4)));
          oacc[d] = __builtin_amdgcn_mfma_f32_16x16x32_bf16(pf, vf, oacc[d], 0, 0, 0);
        }
      }
    }
    __syncthreads();   // drains vmcnt(0) (next tile staged) + all waves done with cur
    cur ^= 1;
  }
#undef STAGE_KV

  // normalize + store o (bf16, row-major [S][DIM])
  float linv[4];
  #pragma unroll
  for (int r = 0; r < 4; ++r) linv[r] = 1.f / lrow[r];
  #pragma unroll
  for (int d = 0; d < 8; ++d) {
    #pragma unroll
    for (int r = 0; r < 4; ++r) {
      size_t row = iw0 + fq * 4 + r;
      size_t col = (size_t)h * HD + d * 16 + fr;
      o[row * DIM + col] = f2bf(oacc[d][r] * linv[r]);
    }
  }
}

extern "C" void kernel_launch(void* const* d_in, const int* in_sizes, int n_in,
                              void* d_out, int out_size, void* d_ws, size_t ws_size,
                              hipStream_t stream) {
  const float* x     = (const float*)d_in[0];
  const float* w_qkv = (const float*)d_in[1];
  const float* w_o   = (const float*)d_in[2];
  float* out = (float*)d_out;

  // workspace layout (128 MiB total, all 16B-aligned)
  u16* xb    = (u16*)d_ws;                          // [4096][2048]
  u16* wqkvT = xb    + (size_t)S_LEN * DIM;         // [6144][2048]
  u16* woT   = wqkvT + (size_t)DIM * N3;            // [2048][2048]
  u16* qkvb  = woT   + (size_t)DIM * DIM;           // [4096][6144]
  u16* vtb   = qkvb  + (size_t)S_LEN * N3;          // [2048][4096]
  u16* ob    = vtb   + (size_t)DIM * S_LEN;         // [4096][2048]

  k_cvt<<<(S_LEN * DIM / 8 + 255) / 256, 256, 0, stream>>>(x, xb, S_LEN * DIM / 8);
  k_trcvt<<<dim3(N3 / 32, DIM / 32), dim3(32, 8), 0, stream>>>(w_qkv, wqkvT, DIM, N3);
  k_trcvt<<<dim3(DIM / 32, DIM / 32), dim3(32, 8), 0, stream>>>(w_o, woT, DIM, DIM);

  k_gemm<1><<<(S_LEN / 128) * (N3 / 128), 256, 0, stream>>>(xb, wqkvT, qkvb, S_LEN, N3, DIM);
  k_trv<<<dim3(DIM / 32, S_LEN / 32), dim3(32, 8), 0, stream>>>(qkvb, vtb);
  k_attn<<<512, 512, 0, stream>>>(qkvb, vtb, ob);
  k_gemm<0><<<(S_LEN / 128) * (DIM / 128), 256, 0, stream>>>(ob, woT, out, S_LEN, DIM, DIM);
}

// Round 5
// 510.509 us; speedup vs baseline: 1.2459x; 1.1463x over previous
//
#include <hip/hip_runtime.h>
#include <stdint.h>

#define S_LEN 4096
#define DIM   2048
#define NH    16
#define HD    128
#define N3    6144

typedef unsigned short u16;
typedef __attribute__((ext_vector_type(8))) short bfrag;   // 8 x bf16 (4 VGPRs)
typedef __attribute__((ext_vector_type(4))) float ffrag;   // 4 x f32 acc

__device__ __forceinline__ u16 f2bf(float f) {
  union { float f; unsigned u; } v; v.f = f;
  unsigned r = v.u + 0x7fffu + ((v.u >> 16) & 1u);  // RNE
  return (u16)(r >> 16);
}

// 2^x via the hardware transcendental (no libm; v_exp_f32 IS exp2)
__device__ __forceinline__ float exp2_hw(float x) {
  float r;
  asm("v_exp_f32 %0, %1" : "=v"(r) : "v"(x));
  return r;
}

__device__ __forceinline__ void gload16(const void* g, void* l) {
  __builtin_amdgcn_global_load_lds((const __attribute__((address_space(1))) void*)g,
                                   (__attribute__((address_space(3))) void*)l, 16, 0, 0);
}

// ---------------- fp32 -> bf16 elementwise ----------------
__global__ void k_cvt(const float* __restrict__ in, u16* __restrict__ out, int n8) {
  int i = blockIdx.x * blockDim.x + threadIdx.x;
  if (i >= n8) return;
  const float4* p = (const float4*)(in + (size_t)i * 8);
  float4 a = p[0], b = p[1];
  bfrag o;
  o[0] = (short)f2bf(a.x); o[1] = (short)f2bf(a.y);
  o[2] = (short)f2bf(a.z); o[3] = (short)f2bf(a.w);
  o[4] = (short)f2bf(b.x); o[5] = (short)f2bf(b.y);
  o[6] = (short)f2bf(b.z); o[7] = (short)f2bf(b.w);
  *(bfrag*)(out + (size_t)i * 8) = o;
}

// ---------------- fp32 [rows][cols] -> bf16 [cols][rows] ----------------
__global__ void k_trcvt(const float* __restrict__ in, u16* __restrict__ out,
                        int rows, int cols) {
  __shared__ float t[32][33];
  int c0 = blockIdx.x * 32, r0 = blockIdx.y * 32;
  int tx = threadIdx.x, ty = threadIdx.y;
  #pragma unroll
  for (int i = ty; i < 32; i += 8)
    t[i][tx] = in[(size_t)(r0 + i) * cols + c0 + tx];
  __syncthreads();
  #pragma unroll
  for (int i = ty; i < 32; i += 8)
    out[(size_t)(c0 + i) * rows + r0 + tx] = f2bf(t[tx][i]);
}

// ---------------- bf16 transpose of V section of qkv -> vt[2048][4096] ----------------
__global__ void k_trv(const u16* __restrict__ qkv, u16* __restrict__ vt) {
  __shared__ u16 t[32][34];
  int c0 = blockIdx.x * 32, r0 = blockIdx.y * 32;  // c: head*D dim, r: s dim
  int tx = threadIdx.x, ty = threadIdx.y;
  #pragma unroll
  for (int i = ty; i < 32; i += 8)
    t[i][tx] = qkv[(size_t)(r0 + i) * N3 + 2 * DIM + c0 + tx];
  __syncthreads();
  #pragma unroll
  for (int i = ty; i < 32; i += 8)
    vt[(size_t)(c0 + i) * S_LEN + r0 + tx] = t[tx][i];
}

// ---------------- bf16 GEMM: C[M][N] = A[M][K] * Bt[N][K]^T ----------------
template<int OUT_BF16>
__global__ __launch_bounds__(256) void k_gemm(const u16* __restrict__ A,
                                              const u16* __restrict__ Bt,
                                              void* __restrict__ C,
                                              int M, int N, int K) {
  __shared__ __align__(16) u16 Al[128 * 64];
  __shared__ __align__(16) u16 Bl[128 * 64];
  const int tid = threadIdx.x;
  const int lane = tid & 63;
  const int w = tid >> 6, wr = w >> 1, wc = w & 1;
  const int fr = lane & 15, fq = lane >> 4;

  // bijective XCD swizzle (m204)
  int nwg = gridDim.x, bid = blockIdx.x;
  int qq = nwg >> 3, r8 = nwg & 7;
  int xcd = bid & 7, ord = bid >> 3;
  int sb = (xcd < r8 ? xcd * (qq + 1) : r8 * (qq + 1) + (xcd - r8) * qq) + ord;
  const int nbx = N >> 7;
  const int bx = sb % nbx, by = sb / nbx;
  const size_t row0 = (size_t)by << 7, col0 = (size_t)bx << 7;

  const int srow = tid >> 3;        // staging row within 32-row round
  const int scb  = (tid & 7) << 4;  // staging byte-col

  ffrag acc[4][4] = {};

  for (int k0 = 0; k0 < K; k0 += 64) {
    __syncthreads();
    #pragma unroll
    for (int r = 0; r < 4; ++r) {
      int trow = r * 32 + srow;
      int cb = scb ^ ((trow & 7) << 4);
      gload16(A + (row0 + trow) * K + k0 + (cb >> 1),
              (char*)Al + r * 4096 + w * 1024);
    }
    #pragma unroll
    for (int r = 0; r < 4; ++r) {
      int trow = r * 32 + srow;
      int cb = scb ^ ((trow & 7) << 4);
      gload16(Bt + (col0 + trow) * K + k0 + (cb >> 1),
              (char*)Bl + r * 4096 + w * 1024);
    }
    __syncthreads();
    #pragma unroll
    for (int kk = 0; kk < 2; ++kk) {
      bfrag af[4], bf[4];
      #pragma unroll
      for (int m = 0; m < 4; ++m) {
        int row = wr * 64 + m * 16 + fr;
        af[m] = *(const bfrag*)((const char*)Al + row * 128 +
                                ((kk * 64 + fq * 16) ^ ((row & 7) << 4)));
      }
      #pragma unroll
      for (int n = 0; n < 4; ++n) {
        int row = wc * 64 + n * 16 + fr;
        bf[n] = *(const bfrag*)((const char*)Bl + row * 128 +
                                ((kk * 64 + fq * 16) ^ ((row & 7) << 4)));
      }
      #pragma unroll
      for (int m = 0; m < 4; ++m)
        #pragma unroll
        for (int n = 0; n < 4; ++n)
          acc[m][n] = __builtin_amdgcn_mfma_f32_16x16x32_bf16(af[m], bf[n], acc[m][n], 0, 0, 0);
    }
  }
  // epilogue: C/D layout col=lane&15, row=(lane>>4)*4+reg  [m89]
  #pragma unroll
  for (int m = 0; m < 4; ++m) {
    size_t grow = row0 + wr * 64 + m * 16 + fq * 4;
    #pragma unroll
    for (int n = 0; n < 4; ++n) {
      size_t gcol = col0 + wc * 64 + n * 16 + fr;
      #pragma unroll
      for (int r = 0; r < 4; ++r) {
        if (OUT_BF16) ((u16*)C)[(grow + r) * N + gcol] = f2bf(acc[m][n][r]);
        else          ((float*)C)[(grow + r) * N + gcol] = acc[m][n][r];
      }
    }
  }
}

// ---------------- flash attention (persistent balanced blocks) ----------------
// grid = 256 = 1 block/CU. Block (x=bid&7, rr=bid>>3): head h = 2x+(rr&1)
// (XCD x touches only heads 2x,2x+1 -> K/V lives in its 4MB L2), q-tile pair
// (31-a, a) with a=rr>>1 -> every block does exactly 68 KV-tile iterations
// (perfect balance by construction, no reliance on dispatcher pairing).
// K/V double-buffered; prefetch pipelined across the q-tile boundary.
__global__ __launch_bounds__(512) void k_attn(const u16* __restrict__ qkv,
                                              const u16* __restrict__ vt,
                                              u16* __restrict__ o) {
  __shared__ __align__(16) u16 Kl[2][64 * 128];   // [j][d] 256B rows, swizzled
  __shared__ __align__(16) u16 Vl[2][128 * 64];   // [d][j] 128B rows, swizzled
  __shared__ __align__(16) u16 Pl[8][16 * 64];    // per-wave P, 128B rows, swizzled
  const int tid = threadIdx.x;
  const int lane = tid & 63;
  const int wq = tid >> 6;           // wave -> 16 q-rows
  const int fr = lane & 15, fq = lane >> 4;

  // persistent-balanced schedule mapping
  const int bid = blockIdx.x;
  const int x = bid & 7, rr = bid >> 3;
  const int h = x * 2 + (rr & 1);
  const int a = rr >> 1;                           // 0..15
  const int qts[2] = {31 - a, a};                  // heavy tile first, then light

  const u16* kbase = qkv + DIM + (size_t)h * HD;
  const u16* vbase = vt + (size_t)h * HD * S_LEN;
  const float sc2 = 0.088388347648318447f * 1.4426950408889634f;  // scale*log2(e)

#define STAGE_KV(J0, KD, VD)                                               \
  do {                                                                     \
    _Pragma("unroll")                                                      \
    for (int r = 0; r < 2; ++r) {                                          \
      int slot = r * 512 + tid;                                            \
      int trow = slot >> 4;                                                \
      int cb = ((slot & 15) << 4) ^ ((trow & 7) << 4);                     \
      gload16(kbase + (size_t)((J0) + trow) * N3 + (cb >> 1),              \
              (char*)(KD) + r * 8192 + wq * 1024);                         \
    }                                                                      \
    _Pragma("unroll")                                                      \
    for (int r = 0; r < 2; ++r) {                                          \
      int slot = r * 512 + tid;                                            \
      int trow = slot >> 3;                                                \
      int cb = ((slot & 7) << 4) ^ ((trow & 7) << 4);                      \
      gload16(vbase + (size_t)trow * S_LEN + (J0) + (cb >> 1),             \
              (char*)(VD) + r * 8192 + wq * 1024);                         \
    }                                                                      \
  } while (0)

  STAGE_KV(0, Kl[0], Vl[0]);       // first tile of q-tile 0 (j0 = 0)
  __syncthreads();                 // drains vmcnt(0): buf0 ready
  int cur = 0;

  for (int t = 0; t < 2; ++t) {
    const int q0 = qts[t] << 7;
    const int iw0 = q0 + wq * 16;                  // wave's first q-row

    // Q fragments in registers (K=128 -> 4 frags)
    bfrag qf[4];
    {
      const u16* qrow = qkv + (size_t)(iw0 + fr) * N3 + h * HD + fq * 8;
      #pragma unroll
      for (int kk = 0; kk < 4; ++kk)
        qf[kk] = *(const bfrag*)(qrow + kk * 32);
    }
    float mrow[4] = {-3e38f, -3e38f, -3e38f, -3e38f};
    float lrow[4] = {0.f, 0.f, 0.f, 0.f};
    ffrag oacc[8] = {};

    int ntiles = (q0 + 192) >> 6;                  // j <= i+1 -> up to q0+128
    if (ntiles > (S_LEN >> 6)) ntiles = S_LEN >> 6;

    for (int jt = 0; jt < ntiles; ++jt) {
      const int j0 = jt << 6;
      // prefetch: next tile of this q-range, or first tile of the next q-range
      if (jt + 1 < ntiles)
        STAGE_KV((jt + 1) << 6, Kl[cur ^ 1], Vl[cur ^ 1]);
      else if (t == 0)
        STAGE_KV(0, Kl[cur ^ 1], Vl[cur ^ 1]);

      const bool active = (j0 <= iw0 + 16);        // wave has any allowed column
      if (active) {
        const char* Kc = (const char*)Kl[cur];
        const char* Vc = (const char*)Vl[cur];
        // S = Q K^T (K rows read as B-fragments)
        ffrag sacc[4] = {};
        #pragma unroll
        for (int n = 0; n < 4; ++n) {
          int row = n * 16 + fr;
          #pragma unroll
          for (int kk = 0; kk < 4; ++kk) {
            bfrag kf = *(const bfrag*)(Kc + row * 256 +
                                       ((kk * 64 + fq * 16) ^ ((row & 7) << 4)));
            sacc[n] = __builtin_amdgcn_mfma_f32_16x16x32_bf16(qf[kk], kf, sacc[n], 0, 0, 0);
          }
        }
        // mask (diagonal tiles only) + row max over raw scores
        const bool needmask = (j0 + 63) > (iw0 + 1);
        float pmax[4] = {-3e38f, -3e38f, -3e38f, -3e38f};
        #pragma unroll
        for (int n = 0; n < 4; ++n) {
          int j = j0 + n * 16 + fr;
          #pragma unroll
          for (int r = 0; r < 4; ++r) {
            float s = sacc[n][r];
            if (needmask) {
              int i = iw0 + fq * 4 + r;
              if (j > i + 1) s = -3e38f;
              sacc[n][r] = s;
            }
            pmax[r] = fmaxf(pmax[r], s);
          }
        }
        #pragma unroll
        for (int r = 0; r < 4; ++r)
          #pragma unroll
          for (int off = 1; off < 16; off <<= 1)
            pmax[r] = fmaxf(pmax[r], __shfl_xor(pmax[r], off));

        // T13 defer-max: rescale only when the new max meaningfully exceeds m
        float needv = fmaxf(fmaxf(pmax[0] - mrow[0], pmax[1] - mrow[1]),
                            fmaxf(pmax[2] - mrow[2], pmax[3] - mrow[3]));
        if (!__all(needv * sc2 <= 8.0f)) {
          #pragma unroll
          for (int r = 0; r < 4; ++r) {
            float mnew = fmaxf(mrow[r], pmax[r]);
            float alpha = exp2_hw((mrow[r] - mnew) * sc2);
            mrow[r] = mnew;
            lrow[r] *= alpha;
            #pragma unroll
            for (int d = 0; d < 8; ++d) oacc[d][r] *= alpha;
          }
        }

        // P = exp2((S - m)*sc2), bf16 into per-wave LDS (swizzled)
        u16* pl = (u16*)Pl[wq];
        float rsum[4] = {0.f, 0.f, 0.f, 0.f};
        #pragma unroll
        for (int n = 0; n < 4; ++n) {
          #pragma unroll
          for (int r = 0; r < 4; ++r) {
            float p = exp2_hw((sacc[n][r] - mrow[r]) * sc2);
            rsum[r] += p;
            int prow = fq * 4 + r;
            int pcb = ((n * 16 + fr) << 1) ^ ((prow & 7) << 4);
            *(u16*)((char*)pl + prow * 128 + pcb) = f2bf(p);
          }
        }
        #pragma unroll
        for (int r = 0; r < 4; ++r) {
          #pragma unroll
          for (int off = 1; off < 16; off <<= 1)
            rsum[r] += __shfl_xor(rsum[r], off);
          lrow[r] += rsum[r];
        }

        asm volatile("s_waitcnt lgkmcnt(0)" ::: "memory");  // P visible to own-wave reads

        // O += P V
        #pragma unroll
        for (int kf2 = 0; kf2 < 2; ++kf2) {
          bfrag pf = *(const bfrag*)((const char*)pl + fr * 128 +
                                     ((kf2 * 64 + fq * 16) ^ ((fr & 7) << 4)));
          #pragma unroll
          for (int d = 0; d < 8; ++d) {
            int row = d * 16 + fr;
            bfrag vf = *(const bfrag*)(Vc + row * 128 +
                                       ((kf2 * 64 + fq * 16) ^ ((row & 7) << 4)));
            oacc[d] = __builtin_amdgcn_mfma_f32_16x16x32_bf16(pf, vf, oacc[d], 0, 0, 0);
          }
        }
      }
      __syncthreads();   // drains vmcnt(0) (next tile staged) + all waves done with cur
      cur ^= 1;
    }

    // normalize + store o for this q-tile (bf16, row-major [S][DIM])
    float linv[4];
    #pragma unroll
    for (int r = 0; r < 4; ++r) linv[r] = 1.f / lrow[r];
    #pragma unroll
    for (int d = 0; d < 8; ++d) {
      #pragma unroll
      for (int r = 0; r < 4; ++r) {
        size_t row = iw0 + fq * 4 + r;
        size_t col = (size_t)h * HD + d * 16 + fr;
        o[row * DIM + col] = f2bf(oacc[d][r] * linv[r]);
      }
    }
  }
#undef STAGE_KV
}

extern "C" void kernel_launch(void* const* d_in, const int* in_sizes, int n_in,
                              void* d_out, int out_size, void* d_ws, size_t ws_size,
                              hipStream_t stream) {
  const float* x     = (const float*)d_in[0];
  const float* w_qkv = (const float*)d_in[1];
  const float* w_o   = (const float*)d_in[2];
  float* out = (float*)d_out;

  // workspace layout (128 MiB total, all 16B-aligned)
  u16* xb    = (u16*)d_ws;                          // [4096][2048]
  u16* wqkvT = xb    + (size_t)S_LEN * DIM;         // [6144][2048]
  u16* woT   = wqkvT + (size_t)DIM * N3;            // [2048][2048]
  u16* qkvb  = woT   + (size_t)DIM * DIM;           // [4096][6144]
  u16* vtb   = qkvb  + (size_t)S_LEN * N3;          // [2048][4096]
  u16* ob    = vtb   + (size_t)DIM * S_LEN;         // [4096][2048]

  k_cvt<<<(S_LEN * DIM / 8 + 255) / 256, 256, 0, stream>>>(x, xb, S_LEN * DIM / 8);
  k_trcvt<<<dim3(N3 / 32, DIM / 32), dim3(32, 8), 0, stream>>>(w_qkv, wqkvT, DIM, N3);
  k_trcvt<<<dim3(DIM / 32, DIM / 32), dim3(32, 8), 0, stream>>>(w_o, woT, DIM, DIM);

  k_gemm<1><<<(S_LEN / 128) * (N3 / 128), 256, 0, stream>>>(xb, wqkvT, qkvb, S_LEN, N3, DIM);
  k_trv<<<dim3(DIM / 32, S_LEN / 32), dim3(32, 8), 0, stream>>>(qkvb, vtb);
  k_attn<<<256, 512, 0, stream>>>(qkvb, vtb, ob);
  k_gemm<0><<<(S_LEN / 128) * (DIM / 128), 256, 0, stream>>>(ob, woT, out, S_LEN, DIM, DIM);
}